// Round 6
// baseline (142.049 us; speedup 1.0000x reference)
//
#include <hip/hip_runtime.h>
#include <hip/hip_bf16.h>

// Problem constants (fixed shapes from the reference)
#define DIN   2048
#define DOUT  2048
#define NTOK  2048
#define NE    8
#define TOPK  2
#define NK    (NTOK*TOPK)        // 4096 flat (token,slot) rows
#define BM    256
#define BN    256
#define BK    64
#define KSPLIT 2
#define KLOC  (DIN/KSPLIT)       // 1024 K per block
#define NKT   (KLOC/BK)          // 16 K-tiles per block
#define NIT   (NKT/2)            // 8 iterations (2 K-tiles each)
#define MAXMT (NK/BM + NE)       // 24 worst-case M-tiles
#define NTN   (DOUT/BN)          // 8 N-tiles
#define NBLK  (MAXMT*NTN*KSPLIT) // 384 (multiple of 8)

#define WEL (NE*DOUT*DIN)        // 33554432 weight elements
#define XEL (NTOK*DIN)           // 4194304 input elements

typedef unsigned short u16;
typedef __attribute__((ext_vector_type(8))) short bf16x8;
typedef __attribute__((ext_vector_type(4))) float f32x4;

// fp32 -> bf16 pair pack: round-half-away (add 0x8000), v_perm grabs high halves.
__device__ __forceinline__ unsigned pack2rn(float a, float b) {
    union { float f; unsigned u; } x, y; x.f = a; y.f = b;
    return __builtin_amdgcn_perm(y.u + 0x8000u, x.u + 0x8000u, 0x07060302u);
}

// async global -> LDS, 16B/lane (wave-uniform LDS base + lane*16; global addr per-lane)
__device__ __forceinline__ void gl_lds16(const void* g, void* l) {
    __builtin_amdgcn_global_load_lds(
        (const __attribute__((address_space(1))) void*)g,
        (__attribute__((address_space(3)))       void*)l, 16, 0, 0);
}

// ---------------- Pass 1: fp32 -> bf16 convert (weight + inputs) ----------------
__global__ __launch_bounds__(256) void cvt_bf16(
    const float* __restrict__ w, const float* __restrict__ x,
    u16* __restrict__ wbf, u16* __restrict__ xbf)
{
    const size_t nch = (size_t)(WEL + XEL) / 8;
    for (size_t c = (size_t)blockIdx.x * blockDim.x + threadIdx.x; c < nch;
         c += (size_t)gridDim.x * blockDim.x) {
        const float* src; u16* dst; size_t off;
        if (c < (size_t)WEL / 8) { src = w; dst = wbf; off = c * 8; }
        else                     { src = x; dst = xbf; off = (c - (size_t)WEL / 8) * 8; }
        float4 f0 = *(const float4*)(src + off);
        float4 f1 = *(const float4*)(src + off + 4);
        uint4 pk;
        pk.x = pack2rn(f0.x, f0.y); pk.y = pack2rn(f0.z, f0.w);
        pk.z = pack2rn(f1.x, f1.y); pk.w = pack2rn(f1.z, f1.w);
        *(uint4*)(dst + off) = pk;
    }
}

// ---------------- Pass 2: 256x256 grouped GEMM, 8-phase deep pipeline ----------------
// Template: per phase {ds_read subtile || stage granules -> s_barrier -> lgkmcnt(0) ->
// 16 MFMA (one C-quadrant x K=64)} -> [vmcnt(6) at phases 4/8] -> s_barrier.
// B-fragments read once per K-tile (PH0, 12 ds_reads) and held in 32 VGPRs.
// Staging ledger (granule = 64 rows = 1 gl_lds/thread, 2/phase):
//   ph0: b1.Aq2,Aq3<-t(2i+1) | ph1: b0.Bo0,Bo1<-t(2i+2) | ph2: b0.Bo2,Bo3
//   ph3: b0.Aq0,Aq1 +vm6     | ph4: b0.Aq2,Aq3          | ph5: b1.Bo0,Bo1<-t(2i+3)
//   ph6: b1.Bo2,Bo3          | ph7: b1.Aq0,Aq1 +vm6
// All stage targets last LDS-read >=1 phase earlier (end-barriers retire reads);
// min stage->read lead = 5 phases; vmcnt(6) leaves exactly the 6 not-yet-needed loads.
__global__ __launch_bounds__(512, 2) void moe_gemm8p(
    const u16* __restrict__ xb,            // [NTOK][DIN] bf16
    const u16* __restrict__ wb,            // [NE][DOUT][DIN] bf16
    const int* __restrict__ sorted_scattered_idxs,
    const int* __restrict__ expert_offsets,
    const float* __restrict__ gates,
    float*     __restrict__ out)
{
    __shared__ u16 L[2][2][BM * BK];       // [buf][A=0/B=1][row*64+col], 128 KiB
    __shared__ int   s_tok[BM];
    __shared__ float s_gate[BM];

    // XCD swizzle: 48 consecutive per XCD; n0 fastest.
    const int bid = blockIdx.x;
    const int swz = (bid & 7) * (NBLK / 8) + (bid >> 3);
    const int n0  = (swz & (NTN - 1)) * BN;
    const int ksl = (swz >> 3) & (KSPLIT - 1);
    const int mt  = swz >> 4;

    int e = -1, m0 = 0, cnt = 0;
    {
        int acc0 = 0, prev = 0;
        for (int i = 0; i < NE; ++i) {
            int end = expert_offsets[i];
            int c = end - prev;
            int t = (c + BM - 1) / BM;
            if (mt < acc0 + t) {
                e = i; m0 = prev + (mt - acc0) * BM;
                cnt = end - m0; if (cnt > BM) cnt = BM;
                break;
            }
            acc0 += t; prev = end;
        }
    }
    if (e < 0) return;   // uniform exit, before any barrier

    const int tid = threadIdx.x;
    if (tid < BM) {
        int idx = (tid < cnt) ? (m0 + tid) : m0;   // clamp ragged rows to valid gather
        int p = sorted_scattered_idxs[idx];
        s_tok[tid]  = p;
        s_gate[tid] = gates[p];
    }
    __syncthreads();

    const int wid = tid >> 6, lane = tid & 63;
    const int kbase = ksl * KLOC;
    const u16* wbE = wb + (size_t)e * DOUT * DIN;

    // Staging sources: granule gr covers rows [gr*64, +64); wave wid writes rows
    // gr*64+wid*8..+8 (1 KiB, linear). Source chunk pre-swizzled (rule 21):
    // LDS[r][c] holds global chunk c ^ (r&7); here r&7 == lane>>3.
    const u16* aP[4]; const u16* bP[4];
    #pragma unroll
    for (int gr = 0; gr < 4; ++gr) {
        int r  = gr * 64 + wid * 8 + (lane >> 3);
        int cg = (lane & 7) ^ (lane >> 3);
        aP[gr] = xb  + (size_t)(s_tok[r] >> 1) * DIN + kbase + cg * 8;
        bP[gr] = wbE + (size_t)(n0 + r) * DIN + kbase + cg * 8;
    }

    // Fragment geometry: 8 waves 2M x 4N; per-wave out 128x64.
    const int wr = wid >> 2, wc = wid & 3;
    const int lr = lane & 15, g = lane >> 4;
    const int xk0 = ((0 + g) ^ (lr & 7)) * 8;   // swizzled chunk, k-slice 0 (u16 units)
    const int xk1 = ((4 + g) ^ (lr & 7)) * 8;   // k-slice 1
    const int arow = wr * 128 + lr;             // + pp*32 + mi*16
    const int brow = wc * 64 + lr;              // + n*16

    f32x4 acc[8][4];
    #pragma unroll
    for (int i = 0; i < 8; ++i)
        #pragma unroll
        for (int j = 0; j < 4; ++j) acc[i][j] = (f32x4)0.0f;

    bf16x8 bfv[8];   // B frags (4 N-frags x 2 k-slices), refreshed at PH0/PH4

#define STG(buf, ab, gr, kt)                                                  \
    gl_lds16((ab ? bP[gr] : aP[gr]) + (kt) * BK,                              \
             &L[buf][ab][((gr) * 64 + wid * 8) * BK])

#define VM6 asm volatile("s_waitcnt vmcnt(6)" ::: "memory");                  \
            __builtin_amdgcn_sched_barrier(0);
#define VM0 asm volatile("s_waitcnt vmcnt(0)" ::: "memory");                  \
            __builtin_amdgcn_sched_barrier(0);

#define PHASE(b, pp, STGS, WAITS)                                             \
    {                                                                         \
        bf16x8 af[4];                                                         \
        if ((pp) == 0) {                                                      \
            _Pragma("unroll")                                                 \
            for (int n = 0; n < 4; ++n) {                                     \
                bfv[2*n+0] = *(const bf16x8*)(&L[b][1][(brow + n*16)*BK + xk0]); \
                bfv[2*n+1] = *(const bf16x8*)(&L[b][1][(brow + n*16)*BK + xk1]); \
            }                                                                 \
        }                                                                     \
        af[0] = *(const bf16x8*)(&L[b][0][(arow + (pp)*32 +  0)*BK + xk0]);   \
        af[1] = *(const bf16x8*)(&L[b][0][(arow + (pp)*32 +  0)*BK + xk1]);   \
        af[2] = *(const bf16x8*)(&L[b][0][(arow + (pp)*32 + 16)*BK + xk0]);   \
        af[3] = *(const bf16x8*)(&L[b][0][(arow + (pp)*32 + 16)*BK + xk1]);   \
        STGS;                                                                 \
        __builtin_amdgcn_s_barrier();                                         \
        asm volatile("s_waitcnt lgkmcnt(0)" ::: "memory");                    \
        __builtin_amdgcn_sched_barrier(0);                                    \
        __builtin_amdgcn_s_setprio(1);                                        \
        _Pragma("unroll")                                                     \
        for (int mi = 0; mi < 2; ++mi)                                        \
            _Pragma("unroll")                                                 \
            for (int n = 0; n < 4; ++n) {                                     \
                acc[(pp)*2+mi][n] = __builtin_amdgcn_mfma_f32_16x16x32_bf16(  \
                    af[mi*2+0], bfv[2*n+0], acc[(pp)*2+mi][n], 0, 0, 0);      \
                acc[(pp)*2+mi][n] = __builtin_amdgcn_mfma_f32_16x16x32_bf16(  \
                    af[mi*2+1], bfv[2*n+1], acc[(pp)*2+mi][n], 0, 0, 0);      \
            }                                                                 \
        __builtin_amdgcn_s_setprio(0);                                        \
        WAITS;                                                                \
        __builtin_amdgcn_s_barrier();                                         \
    }

    // ---- prologue: tile0 fully (8 loads, oldest) + tile1 {Bo0-3, Aq0, Aq1} (6)
    STG(0,1,0,0); STG(0,1,1,0); STG(0,1,2,0); STG(0,1,3,0);
    STG(0,0,0,0); STG(0,0,1,0); STG(0,0,2,0); STG(0,0,3,0);
    STG(1,1,0,1); STG(1,1,1,1); STG(1,1,2,1); STG(1,1,3,1);
    STG(1,0,0,1); STG(1,0,1,1);
    VM6;
    __builtin_amdgcn_s_barrier();

    for (int it = 0; it < NIT - 1; ++it) {
        const int t1 = 2*it + 1, t2 = 2*it + 2, t3 = 2*it + 3;
        PHASE(0,0, STG(1,0,2,t1); STG(1,0,3,t1), )
        PHASE(0,1, STG(0,1,0,t2); STG(0,1,1,t2), )
        PHASE(0,2, STG(0,1,2,t2); STG(0,1,3,t2), )
        PHASE(0,3, STG(0,0,0,t2); STG(0,0,1,t2), VM6)
        PHASE(1,0, STG(0,0,2,t2); STG(0,0,3,t2), )
        PHASE(1,1, STG(1,1,0,t3); STG(1,1,1,t3), )
        PHASE(1,2, STG(1,1,2,t3); STG(1,1,3,t3), )
        PHASE(1,3, STG(1,0,0,t3); STG(1,0,1,t3), VM6)
    }
    { // tail iteration: finish tile 2*NIT-1; no further stages
        const int t1 = 2*(NIT-1) + 1;
        PHASE(0,0, STG(1,0,2,t1); STG(1,0,3,t1), )
        PHASE(0,1, ((void)0), )
        PHASE(0,2, ((void)0), )
        PHASE(0,3, ((void)0), VM0)
        PHASE(1,0, ((void)0), )
        PHASE(1,1, ((void)0), )
        PHASE(1,2, ((void)0), )
        PHASE(1,3, ((void)0), )
    }

#undef STG
#undef VM6
#undef VM0
#undef PHASE

    // ---- epilogue: out[token] += gate * y  (TOPK x KSPLIT contributions)
    #pragma unroll
    for (int i = 0; i < 8; ++i) {
        #pragma unroll
        for (int r = 0; r < 4; ++r) {
            int lrow = wr * 128 + i * 16 + g * 4 + r;
            if (lrow < cnt) {
                int   p  = s_tok[lrow];
                float gf = s_gate[lrow];
                float* orow = out + (size_t)(p >> 1) * DOUT + n0 + wc * 64;
                #pragma unroll
                for (int j = 0; j < 4; ++j)
                    atomicAdd(orow + j * 16 + lr, gf * acc[i][j][r]);
            }
        }
    }
}

// ---------------- Fallback: fused fp32-in kernel (used if ws too small) ----------------
#define FBM 128
#define FBK 64
__global__ __launch_bounds__(256, 3) void moe_gemm_fused(
    const float* __restrict__ inputs, const float* __restrict__ weight,
    const int* __restrict__ sorted_scattered_idxs, const int* __restrict__ expert_offsets,
    const float* __restrict__ gates, float* __restrict__ out)
{
    __shared__ u16 As[FBM * FBK];
    __shared__ u16 Bs[FBM * FBK];
    __shared__ int   s_tok[FBM];
    __shared__ float s_gate[FBM];

    const int mt = blockIdx.y;
    const int n0 = blockIdx.x * FBM;
    int e = -1, m0 = 0, cnt = 0;
    {
        int acc = 0, prev = 0;
        for (int i = 0; i < NE; ++i) {
            int end = expert_offsets[i];
            int c = end - prev;
            int t = (c + FBM - 1) / FBM;
            if (mt < acc + t) {
                e = i; m0 = prev + (mt - acc) * FBM;
                cnt = end - m0; if (cnt > FBM) cnt = FBM;
                break;
            }
            acc += t; prev = end;
        }
    }
    if (e < 0) return;

    const int tid = threadIdx.x;
    if (tid < FBM) {
        int idx = (tid < cnt) ? (m0 + tid) : m0;
        int p = sorted_scattered_idxs[idx];
        s_tok[tid]  = p;
        s_gate[tid] = gates[p];
    }
    __syncthreads();

    const int ch  = tid & 7;
    const int r0  = tid >> 3;
    const int sch = ch ^ (r0 & 7);
    const float* wbase = weight + (size_t)e * DOUT * DIN;
    const float* ap[4]; const float* bp[4];
    #pragma unroll
    for (int i = 0; i < 4; ++i) {
        int r = r0 + 32 * i;
        ap[i] = inputs + (size_t)(s_tok[r] >> 1) * DIN + ch * 8;
        bp[i] = wbase + (size_t)(n0 + r) * DIN + ch * 8;
    }
    u16* aw = &As[r0 * FBK + sch * 8];
    u16* bw = &Bs[r0 * FBK + sch * 8];

    const int wid = tid >> 6, lane = tid & 63;
    const int wm = (wid >> 1) * 64, wn = (wid & 1) * 64;
    const int g  = lane >> 4, lr = lane & 15;

    f32x4 acc[4][4];
    #pragma unroll
    for (int i = 0; i < 4; ++i)
        #pragma unroll
        for (int j = 0; j < 4; ++j) acc[i][j] = (f32x4)0.0f;

    float4 pa[4][2], pb[4][2];
    #pragma unroll
    for (int i = 0; i < 4; ++i) {
        pa[i][0] = *(const float4*)(ap[i] + 0); pa[i][1] = *(const float4*)(ap[i] + 4);
        pb[i][0] = *(const float4*)(bp[i] + 0); pb[i][1] = *(const float4*)(bp[i] + 4);
    }
    for (int kt = 0; kt < DIN / FBK; ++kt) {
        __syncthreads();
        #pragma unroll
        for (int i = 0; i < 4; ++i) {
            uint4 va, vb;
            va.x = pack2rn(pa[i][0].x, pa[i][0].y); va.y = pack2rn(pa[i][0].z, pa[i][0].w);
            va.z = pack2rn(pa[i][1].x, pa[i][1].y); va.w = pack2rn(pa[i][1].z, pa[i][1].w);
            *(uint4*)(aw + i * 32 * FBK) = va;
            vb.x = pack2rn(pb[i][0].x, pb[i][0].y); vb.y = pack2rn(pb[i][0].z, pb[i][0].w);
            vb.z = pack2rn(pb[i][1].x, pb[i][1].y); vb.w = pack2rn(pb[i][1].z, pb[i][1].w);
            *(uint4*)(bw + i * 32 * FBK) = vb;
        }
        __syncthreads();
        if (kt + 1 < DIN / FBK) {
            const int kof = (kt + 1) * FBK;
            #pragma unroll
            for (int i = 0; i < 4; ++i) {
                pa[i][0] = *(const float4*)(ap[i] + kof); pa[i][1] = *(const float4*)(ap[i] + kof + 4);
                pb[i][0] = *(const float4*)(bp[i] + kof); pb[i][1] = *(const float4*)(bp[i] + kof + 4);
            }
        }
        #pragma unroll
        for (int ks = 0; ks < 2; ++ks) {
            bf16x8 a[4], b[4];
            #pragma unroll
            for (int i = 0; i < 4; ++i) {
                int ra = wm + i * 16 + lr; int ca = (ks * 4 + g) ^ (ra & 7);
                a[i] = *(const bf16x8*)(&As[ra * FBK + ca * 8]);
                int rb = wn + i * 16 + lr; int cb = (ks * 4 + g) ^ (rb & 7);
                b[i] = *(const bf16x8*)(&Bs[rb * FBK + cb * 8]);
            }
            #pragma unroll
            for (int i = 0; i < 4; ++i)
                #pragma unroll
                for (int j = 0; j < 4; ++j)
                    acc[i][j] = __builtin_amdgcn_mfma_f32_16x16x32_bf16(a[i], b[j], acc[i][j], 0, 0, 0);
        }
    }
    #pragma unroll
    for (int i = 0; i < 4; ++i) {
        #pragma unroll
        for (int j2 = 0; j2 < 4; ++j2) {
            int lrow = wm + i * 16 + g * 4 + j2;
            if (lrow < cnt) {
                int   p  = s_tok[lrow];
                float gf = s_gate[lrow];
                float* orow = out + (size_t)(p >> 1) * DOUT + n0 + wn;
                #pragma unroll
                for (int nf = 0; nf < 4; ++nf)
                    atomicAdd(orow + nf * 16 + lr, gf * acc[i][nf][j2]);
            }
        }
    }
}

extern "C" void kernel_launch(void* const* d_in, const int* in_sizes, int n_in,
                              void* d_out, int out_size, void* d_ws, size_t ws_size,
                              hipStream_t stream) {
    const float* inputs  = (const float*)d_in[0];
    const float* weight  = (const float*)d_in[1];
    const int*   ssi     = (const int*)d_in[4];
    const int*   eoff    = (const int*)d_in[6];
    const float* gates   = (const float*)d_in[7];
    float* out = (float*)d_out;

    hipMemsetAsync(out, 0, (size_t)out_size * sizeof(float), stream);

    const size_t need = ((size_t)WEL + (size_t)XEL) * sizeof(u16);  // 75.5 MB
    if (ws_size >= need) {
        u16* wbf = (u16*)d_ws;
        u16* xbf = wbf + (size_t)WEL;
        cvt_bf16<<<2048, 256, 0, stream>>>(weight, inputs, wbf, xbf);
        moe_gemm8p<<<NBLK, 512, 0, stream>>>(xbf, wbf, ssi, eoff, gates, out);
    } else {
        dim3 grid(DOUT / FBM, NK / FBM + NE);
        moe_gemm_fused<<<grid, 256, 0, stream>>>(inputs, weight, ssi, eoff, gates, out);
    }
}

// Round 7
// 113.155 us; speedup vs baseline: 1.2553x; 1.2553x over previous
//
#include <hip/hip_runtime.h>
#include <hip/hip_bf16.h>

// Problem constants (fixed shapes from the reference)
#define DIN   2048
#define DOUT  2048
#define NTOK  2048
#define NE    8
#define TOPK  2
#define NK    (NTOK*TOPK)        // 4096 flat (token,slot) rows
#define BM    128
#define BN    128
#define BK    64
#define NKT   (DIN/BK)           // 32 K-tiles
#define MAXMT (NK/BM + NE)       // 40 worst-case M-tiles
#define NTN   (DOUT/BN)          // 16 N-tiles
#define NBLK  (MAXMT*NTN)        // 640 (multiple of 8)

#define WEL (NE*DOUT*DIN)        // 33554432 weight elements
#define XEL (NTOK*DIN)           // 4194304 input elements

typedef unsigned short u16;
typedef __attribute__((ext_vector_type(8))) short bf16x8;
typedef __attribute__((ext_vector_type(4))) float f32x4;

// fp32 -> bf16 pair pack: round-half-away (add 0x8000), v_perm grabs high halves.
__device__ __forceinline__ unsigned pack2rn(float a, float b) {
    union { float f; unsigned u; } x, y; x.f = a; y.f = b;
    return __builtin_amdgcn_perm(y.u + 0x8000u, x.u + 0x8000u, 0x07060302u);
}

// async global -> LDS, 16B/lane (wave-uniform LDS base; HW adds lane*16; global addr per-lane)
__device__ __forceinline__ void gl_lds16(const void* g, void* l) {
    __builtin_amdgcn_global_load_lds(
        (const __attribute__((address_space(1))) void*)g,
        (__attribute__((address_space(3)))       void*)l, 16, 0, 0);
}

// ---------------- Pass 1: fp32 -> bf16 convert (weight + inputs) ----------------
__global__ __launch_bounds__(256) void cvt_bf16(
    const float* __restrict__ w, const float* __restrict__ x,
    u16* __restrict__ wbf, u16* __restrict__ xbf)
{
    const size_t nch = (size_t)(WEL + XEL) / 8;
    for (size_t c = (size_t)blockIdx.x * blockDim.x + threadIdx.x; c < nch;
         c += (size_t)gridDim.x * blockDim.x) {
        const float* src; u16* dst; size_t off;
        if (c < (size_t)WEL / 8) { src = w; dst = wbf; off = c * 8; }
        else                     { src = x; dst = xbf; off = (c - (size_t)WEL / 8) * 8; }
        float4 f0 = *(const float4*)(src + off);
        float4 f1 = *(const float4*)(src + off + 4);
        uint4 pk;
        pk.x = pack2rn(f0.x, f0.y); pk.y = pack2rn(f0.z, f0.w);
        pk.z = pack2rn(f1.x, f1.y); pk.w = pack2rn(f1.z, f1.w);
        *(uint4*)(dst + off) = pk;
    }
}

// ---------------- Pass 2: 128x128 grouped GEMM, TLP-first ----------------
// 512 threads (8 waves 2Mx4N, 64x32 out/wave), dbuf 64 KB LDS -> 2 blocks/CU
// resident = 4 waves/SIMD. Counted vmcnt(4): tile t+1's 4 loads stay in flight
// across the loop-head barrier; stage t+2 issues after the post-MFMA barrier
// (all reads of buf t&1 retired: every wave passed lgkmcnt(0) before it).
__global__ __launch_bounds__(512, 4) void moe_gemm_tlp(
    const u16* __restrict__ xb,            // [NTOK][DIN] bf16
    const u16* __restrict__ wb,            // [NE][DOUT][DIN] bf16
    const int* __restrict__ sorted_scattered_idxs,
    const int* __restrict__ expert_offsets,
    const float* __restrict__ gates,
    float*     __restrict__ out)
{
    __shared__ u16 As[2][BM * BK];         // 16 KB each
    __shared__ u16 Bs[2][BN * BK];
    __shared__ int   s_tok[BM];
    __shared__ float s_gate[BM];

    // Bijective XCD swizzle (640 = 8*80); n0 fastest -> the 16 jobs sharing an
    // A-panel (same mt) are consecutive on one XCD (A L2-reuse x16).
    const int bid = blockIdx.x;
    const int swz = (bid & 7) * (NBLK / 8) + (bid >> 3);
    const int n0  = (swz & (NTN - 1)) * BN;
    const int mt  = swz >> 4;

    int e = -1, m0 = 0, cnt = 0;
    {
        int acc0 = 0, prev = 0;
        for (int i = 0; i < NE; ++i) {
            int end = expert_offsets[i];
            int c = end - prev;
            int t = (c + BM - 1) / BM;
            if (mt < acc0 + t) {
                e = i; m0 = prev + (mt - acc0) * BM;
                cnt = end - m0; if (cnt > BM) cnt = BM;
                break;
            }
            acc0 += t; prev = end;
        }
    }
    if (e < 0) return;   // uniform exit before any barrier

    const int tid = threadIdx.x;
    if (tid < BM) {
        int idx = (tid < cnt) ? (m0 + tid) : m0;   // clamp ragged rows to valid gather
        int p = sorted_scattered_idxs[idx];
        s_tok[tid]  = p;
        s_gate[tid] = gates[p];
    }
    __syncthreads();

    const int wid = tid >> 6, lane = tid & 63;

    // ---- staging geometry: 2 chunks/thread per matrix per K-tile.
    // chunk id c = tid + s*512 -> row=c>>3, ch=c&7; source chunk pre-swizzled
    // cg = ch ^ (row&7) (rule 21: LDS stays linear; LDS[r][x]=global[x^(r&7)]).
    const u16* wbE = wb + (size_t)e * DOUT * DIN;
    const int ch   = tid & 7;
    const int row0 = tid >> 3;                 // s=0 row; s=1 row = row0+64 (same &7)
    const int cg   = ch ^ (row0 & 7);
    const u16* aS[2]; const u16* bS[2];
    #pragma unroll
    for (int s = 0; s < 2; ++s) {
        int r = row0 + s * 64;
        aS[s] = xb  + (size_t)(s_tok[r] >> 1) * DIN + cg * 8;
        bS[s] = wbE + (size_t)(n0 + r) * DIN + cg * 8;
    }
    const int dst0 = wid * 512;                // wave-uniform LDS base (u16), s=0
    const int dst1 = wid * 512 + 4096;         // s=1

    // ---- fragment geometry: wave out 64x32 at (wr*64, wc*32)
    const int wr = wid >> 2, wc = wid & 3;
    const int lr = lane & 15, g = lane >> 4;
    const int xk0 = ((0 + g) ^ (lr & 7)) * 8;  // swizzled k-chunk, slice 0 (u16 units)
    const int xk1 = ((4 + g) ^ (lr & 7)) * 8;  // slice 1
    int aoff[4], boff[2];
    #pragma unroll
    for (int mi = 0; mi < 4; ++mi) aoff[mi] = (wr * 64 + mi * 16 + lr) * BK;
    #pragma unroll
    for (int n = 0; n < 2; ++n)    boff[n]  = (wc * 32 + n * 16 + lr) * BK;

    f32x4 acc[4][2];
    #pragma unroll
    for (int mi = 0; mi < 4; ++mi)
        #pragma unroll
        for (int n = 0; n < 2; ++n) acc[mi][n] = (f32x4)0.0f;

#define STG(buf, t)                                                           \
    {                                                                         \
        const int ko = (t) * BK;                                              \
        gl_lds16(aS[0] + ko, &As[buf][dst0]);                                 \
        gl_lds16(aS[1] + ko, &As[buf][dst1]);                                 \
        gl_lds16(bS[0] + ko, &Bs[buf][dst0]);                                 \
        gl_lds16(bS[1] + ko, &Bs[buf][dst1]);                                 \
    }

#define BODY(t)                                                               \
    {                                                                         \
        const int b = (t) & 1;                                                \
        bf16x8 af[4][2], bf[2][2];                                            \
        _Pragma("unroll")                                                     \
        for (int mi = 0; mi < 4; ++mi) {                                      \
            af[mi][0] = *(const bf16x8*)(&As[b][aoff[mi] + xk0]);             \
            af[mi][1] = *(const bf16x8*)(&As[b][aoff[mi] + xk1]);             \
        }                                                                     \
        _Pragma("unroll")                                                     \
        for (int n = 0; n < 2; ++n) {                                         \
            bf[n][0] = *(const bf16x8*)(&Bs[b][boff[n] + xk0]);               \
            bf[n][1] = *(const bf16x8*)(&Bs[b][boff[n] + xk1]);               \
        }                                                                     \
        asm volatile("s_waitcnt lgkmcnt(0)" ::: "memory");                    \
        __builtin_amdgcn_sched_barrier(0);                                    \
        __builtin_amdgcn_s_setprio(1);                                        \
        _Pragma("unroll")                                                     \
        for (int mi = 0; mi < 4; ++mi)                                        \
            _Pragma("unroll")                                                 \
            for (int n = 0; n < 2; ++n) {                                     \
                acc[mi][n] = __builtin_amdgcn_mfma_f32_16x16x32_bf16(         \
                    af[mi][0], bf[n][0], acc[mi][n], 0, 0, 0);                \
                acc[mi][n] = __builtin_amdgcn_mfma_f32_16x16x32_bf16(         \
                    af[mi][1], bf[n][1], acc[mi][n], 0, 0, 0);                \
            }                                                                 \
        __builtin_amdgcn_s_setprio(0);                                        \
        __builtin_amdgcn_s_barrier();                                         \
    }

    // prologue: tiles 0 and 1 in flight (8 loads/thread)
    STG(0, 0);
    STG(1, 1);

    for (int t = 0; t < NKT - 2; ++t) {
        asm volatile("s_waitcnt vmcnt(4)" ::: "memory");   // tile t landed; t+1 in flight
        __builtin_amdgcn_sched_barrier(0);
        __builtin_amdgcn_s_barrier();
        BODY(t);
        STG(t & 1, t + 2);              // after post-MFMA barrier: buf t&1 free
    }
    {   // t = NKT-2: nothing left to stage
        asm volatile("s_waitcnt vmcnt(4)" ::: "memory");
        __builtin_amdgcn_sched_barrier(0);
        __builtin_amdgcn_s_barrier();
        BODY(NKT - 2);
    }
    {   // t = NKT-1: only its own 4 loads outstanding
        asm volatile("s_waitcnt vmcnt(0)" ::: "memory");
        __builtin_amdgcn_sched_barrier(0);
        __builtin_amdgcn_s_barrier();
        BODY(NKT - 1);
    }

#undef STG
#undef BODY

    // ---- epilogue: out[token] += gate * y  (TOPK contributions accumulate)
    #pragma unroll
    for (int mi = 0; mi < 4; ++mi) {
        #pragma unroll
        for (int r = 0; r < 4; ++r) {
            int lrow = wr * 64 + mi * 16 + g * 4 + r;
            if (lrow < cnt) {
                int   p  = s_tok[lrow];
                float gf = s_gate[lrow];
                float* orow = out + (size_t)(p >> 1) * DOUT + n0 + wc * 32;
                #pragma unroll
                for (int n = 0; n < 2; ++n)
                    atomicAdd(orow + n * 16 + lr, gf * acc[mi][n][r]);
            }
        }
    }
}

// ---------------- Fallback: fused fp32-in kernel (used if ws too small) ----------------
#define FBM 128
#define FBK 64
__global__ __launch_bounds__(256, 3) void moe_gemm_fused(
    const float* __restrict__ inputs, const float* __restrict__ weight,
    const int* __restrict__ sorted_scattered_idxs, const int* __restrict__ expert_offsets,
    const float* __restrict__ gates, float* __restrict__ out)
{
    __shared__ u16 As[FBM * FBK];
    __shared__ u16 Bs[FBM * FBK];
    __shared__ int   s_tok[FBM];
    __shared__ float s_gate[FBM];

    const int mt = blockIdx.y;
    const int n0 = blockIdx.x * FBM;
    int e = -1, m0 = 0, cnt = 0;
    {
        int acc = 0, prev = 0;
        for (int i = 0; i < NE; ++i) {
            int end = expert_offsets[i];
            int c = end - prev;
            int t = (c + FBM - 1) / FBM;
            if (mt < acc + t) {
                e = i; m0 = prev + (mt - acc) * FBM;
                cnt = end - m0; if (cnt > FBM) cnt = FBM;
                break;
            }
            acc += t; prev = end;
        }
    }
    if (e < 0) return;

    const int tid = threadIdx.x;
    if (tid < FBM) {
        int idx = (tid < cnt) ? (m0 + tid) : m0;
        int p = sorted_scattered_idxs[idx];
        s_tok[tid]  = p;
        s_gate[tid] = gates[p];
    }
    __syncthreads();

    const int ch  = tid & 7;
    const int r0  = tid >> 3;
    const int sch = ch ^ (r0 & 7);
    const float* wbase = weight + (size_t)e * DOUT * DIN;
    const float* ap[4]; const float* bp[4];
    #pragma unroll
    for (int i = 0; i < 4; ++i) {
        int r = r0 + 32 * i;
        ap[i] = inputs + (size_t)(s_tok[r] >> 1) * DIN + ch * 8;
        bp[i] = wbase + (size_t)(n0 + r) * DIN + ch * 8;
    }
    u16* aw = &As[r0 * FBK + sch * 8];
    u16* bw = &Bs[r0 * FBK + sch * 8];

    const int wid = tid >> 6, lane = tid & 63;
    const int wm = (wid >> 1) * 64, wn = (wid & 1) * 64;
    const int g  = lane >> 4, lr = lane & 15;

    f32x4 acc[4][4];
    #pragma unroll
    for (int i = 0; i < 4; ++i)
        #pragma unroll
        for (int j = 0; j < 4; ++j) acc[i][j] = (f32x4)0.0f;

    float4 pa[4][2], pb[4][2];
    #pragma unroll
    for (int i = 0; i < 4; ++i) {
        pa[i][0] = *(const float4*)(ap[i] + 0); pa[i][1] = *(const float4*)(ap[i] + 4);
        pb[i][0] = *(const float4*)(bp[i] + 0); pb[i][1] = *(const float4*)(bp[i] + 4);
    }
    for (int kt = 0; kt < DIN / FBK; ++kt) {
        __syncthreads();
        #pragma unroll
        for (int i = 0; i < 4; ++i) {
            uint4 va, vb;
            va.x = pack2rn(pa[i][0].x, pa[i][0].y); va.y = pack2rn(pa[i][0].z, pa[i][0].w);
            va.z = pack2rn(pa[i][1].x, pa[i][1].y); va.w = pack2rn(pa[i][1].z, pa[i][1].w);
            *(uint4*)(aw + i * 32 * FBK) = va;
            vb.x = pack2rn(pb[i][0].x, pb[i][0].y); vb.y = pack2rn(pb[i][0].z, pb[i][0].w);
            vb.z = pack2rn(pb[i][1].x, pb[i][1].y); vb.w = pack2rn(pb[i][1].z, pb[i][1].w);
            *(uint4*)(bw + i * 32 * FBK) = vb;
        }
        __syncthreads();
        if (kt + 1 < DIN / FBK) {
            const int kof = (kt + 1) * FBK;
            #pragma unroll
            for (int i = 0; i < 4; ++i) {
                pa[i][0] = *(const float4*)(ap[i] + kof); pa[i][1] = *(const float4*)(ap[i] + kof + 4);
                pb[i][0] = *(const float4*)(bp[i] + kof); pb[i][1] = *(const float4*)(bp[i] + kof + 4);
            }
        }
        #pragma unroll
        for (int ks = 0; ks < 2; ++ks) {
            bf16x8 a[4], b[4];
            #pragma unroll
            for (int i = 0; i < 4; ++i) {
                int ra = wm + i * 16 + lr; int ca = (ks * 4 + g) ^ (ra & 7);
                a[i] = *(const bf16x8*)(&As[ra * FBK + ca * 8]);
                int rb = wn + i * 16 + lr; int cb = (ks * 4 + g) ^ (rb & 7);
                b[i] = *(const bf16x8*)(&Bs[rb * FBK + cb * 8]);
            }
            #pragma unroll
            for (int i = 0; i < 4; ++i)
                #pragma unroll
                for (int j = 0; j < 4; ++j)
                    acc[i][j] = __builtin_amdgcn_mfma_f32_16x16x32_bf16(a[i], b[j], acc[i][j], 0, 0, 0);
        }
    }
    #pragma unroll
    for (int i = 0; i < 4; ++i) {
        #pragma unroll
        for (int j2 = 0; j2 < 4; ++j2) {
            int lrow = wm + i * 16 + g * 4 + j2;
            if (lrow < cnt) {
                int   p  = s_tok[lrow];
                float gf = s_gate[lrow];
                float* orow = out + (size_t)(p >> 1) * DOUT + n0 + wn;
                #pragma unroll
                for (int nf = 0; nf < 4; ++nf)
                    atomicAdd(orow + nf * 16 + lr, gf * acc[i][nf][j2]);
            }
        }
    }
}

extern "C" void kernel_launch(void* const* d_in, const int* in_sizes, int n_in,
                              void* d_out, int out_size, void* d_ws, size_t ws_size,
                              hipStream_t stream) {
    const float* inputs  = (const float*)d_in[0];
    const float* weight  = (const float*)d_in[1];
    const int*   ssi     = (const int*)d_in[4];
    const int*   eoff    = (const int*)d_in[6];
    const float* gates   = (const float*)d_in[7];
    float* out = (float*)d_out;

    hipMemsetAsync(out, 0, (size_t)out_size * sizeof(float), stream);

    const size_t need = ((size_t)WEL + (size_t)XEL) * sizeof(u16);  // 75.5 MB
    if (ws_size >= need) {
        u16* wbf = (u16*)d_ws;
        u16* xbf = wbf + (size_t)WEL;
        cvt_bf16<<<2048, 256, 0, stream>>>(weight, inputs, wbf, xbf);
        moe_gemm_tlp<<<NBLK, 512, 0, stream>>>(xbf, wbf, ssi, eoff, gates, out);
    } else {
        dim3 grid(DOUT / FBM, NK / FBM + NE);
        moe_gemm_fused<<<grid, 256, 0, stream>>>(inputs, weight, ssi, eoff, gates, out);
    }
}